// Round 4
// baseline (543.696 us; speedup 1.0000x reference)
//
#include <hip/hip_runtime.h>
#include <cstdint>

// TCNN hash-grid fwd, R4 (= R3 with ext_vector types for nontemporal builtins):
// bf16-packed tables in ws (L2 residency), x-pair coalesced gathers,
// nontemporal streaming, interleave fused into level-7.

constexpr int      kBatch   = 2097152;
constexpr uint32_t kHash    = 1u << 19;
constexpr size_t   kWsNeed  = (size_t)(16 + 112) * 1024 * 1024; // bt + 7 planes

typedef float    f32x2 __attribute__((ext_vector_type(2)));
typedef float    f32x4 __attribute__((ext_vector_type(4)));
typedef uint32_t u32x2 __attribute__((ext_vector_type(2)));

__device__ __forceinline__ uint32_t bf16rn(float f) {
    uint32_t u = __float_as_uint(f);
    return (u + 0x7FFFu + ((u >> 16) & 1u)) >> 16;
}
__device__ __forceinline__ float bf_lo(uint32_t w) {
    return __uint_as_float(w << 16);
}
__device__ __forceinline__ float bf_hi(uint32_t w) {
    return __uint_as_float(w & 0xFFFF0000u);
}

// ---- pack f32 table [8,2^19,2] -> bf16x2 words [8,2^19] ----
__global__ __launch_bounds__(256) void convert_tables(
    const float* __restrict__ table, uint32_t* __restrict__ bt)
{
    const size_t i = (size_t)blockIdx.x * 256 + threadIdx.x; // 2 entries each
    const f32x4 v = __builtin_nontemporal_load(
        reinterpret_cast<const f32x4*>(table) + i);
    u32x2 o;
    o.x = bf16rn(v.x) | (bf16rn(v.y) << 16);
    o.y = bf16rn(v.z) | (bf16rn(v.w) << 16);
    __builtin_nontemporal_store(o, reinterpret_cast<u32x2*>(bt) + i);
}

// ---- hashed level (bf16 table). FUSE_OUT: also do final interleave ----
template <uint32_t RES, bool FUSE_OUT>
__global__ __launch_bounds__(256) void hash_level_b(
    const float* __restrict__ xs,
    const uint32_t* __restrict__ tl,       // this level's bf16x2 table
    float* __restrict__ plane,             // !FUSE_OUT: planar dst
    const float* __restrict__ planes,      // FUSE_OUT: planar levels 0..6
    float* __restrict__ out)
{
    const int p = blockIdx.x * 256 + threadIdx.x;

    const float px = __builtin_nontemporal_load(xs + 3 * p + 0);
    const float py = __builtin_nontemporal_load(xs + 3 * p + 1);
    const float pz = __builtin_nontemporal_load(xs + 3 * p + 2);

    const float scale = (float)(RES - 1u);
    const float fx = px * scale + 0.5f;
    const float fy = py * scale + 0.5f;
    const float fz = pz * scale + 0.5f;
    const float flx = floorf(fx), fly = floorf(fy), flz = floorf(fz);
    const float rx = fx - flx, ry = fy - fly, rz = fz - flz;
    const uint32_t bx = (uint32_t)flx;
    const uint32_t by = (uint32_t)fly;
    const uint32_t bz = (uint32_t)flz;

    const uint32_t hy0 = by * 2654435761u, hy1 = (by + 1u) * 2654435761u;
    const uint32_t hz0 = bz * 805459861u,  hz1 = (bz + 1u) * 805459861u;
    uint32_t hyz[4] = {hy0 ^ hz0, hy1 ^ hz0, hy0 ^ hz1, hy1 ^ hz1};

    uint32_t i0[4];
#pragma unroll
    for (int k = 0; k < 4; ++k) i0[k] = (bx ^ hyz[k]) & (kHash - 1u);

    u32x2 v[4];
#pragma unroll
    for (int k = 0; k < 4; ++k)
        v[k] = *reinterpret_cast<const u32x2*>(tl + (i0[k] & ~1u));

    const bool bxodd = (bx & 1u) != 0u;
    uint32_t e0[4], e1[4];
    if (bxodd) {
#pragma unroll
        for (int k = 0; k < 4; ++k)
            e1[k] = tl[((bx + 1u) ^ hyz[k]) & (kHash - 1u)];
    }
#pragma unroll
    for (int k = 0; k < 4; ++k) {
        const bool lo = (i0[k] & 1u) != 0u;
        e0[k] = lo ? v[k].y : v[k].x;
        if (!bxodd) e1[k] = lo ? v[k].x : v[k].y;   // idx^1 partner
    }

    const float wx0 = 1.0f - rx, wx1 = rx;
    const float wyz[4] = {(1.0f - ry) * (1.0f - rz), ry * (1.0f - rz),
                          (1.0f - ry) * rz,          ry * rz};
    float a0 = 0.0f, a1 = 0.0f;
#pragma unroll
    for (int k = 0; k < 4; ++k) {
        const float w0 = wx0 * wyz[k], w1 = wx1 * wyz[k];
        a0 = fmaf(bf_lo(e0[k]), w0, fmaf(bf_lo(e1[k]), w1, a0));
        a1 = fmaf(bf_hi(e0[k]), w0, fmaf(bf_hi(e1[k]), w1, a1));
    }

    if (!FUSE_OUT) {
        f32x2 r; r.x = a0; r.y = a1;
        __builtin_nontemporal_store(r, reinterpret_cast<f32x2*>(plane) + p);
    } else {
        float vrow[16];
#pragma unroll
        for (int l = 0; l < 7; ++l) {
            const f32x2 t = __builtin_nontemporal_load(
                reinterpret_cast<const f32x2*>(planes + (size_t)l * kBatch * 2) + p);
            vrow[2 * l + 0] = t.x;
            vrow[2 * l + 1] = t.y;
        }
        vrow[14] = a0;
        vrow[15] = a1;
        f32x4* op = reinterpret_cast<f32x4*>(out + (size_t)p * 16u);
#pragma unroll
        for (int i = 0; i < 4; ++i) {
            f32x4 q;
            q.x = vrow[4 * i + 0]; q.y = vrow[4 * i + 1];
            q.z = vrow[4 * i + 2]; q.w = vrow[4 * i + 3];
            __builtin_nontemporal_store(q, op + i);
        }
    }
}

// ---- dense levels 0..2 fused (bf16 tables), planar out ----
__global__ __launch_bounds__(256) void dense_levels_b(
    const float* __restrict__ xs,
    const uint32_t* __restrict__ bt,   // all 8 bf16x2 tables
    float* __restrict__ planes)        // planar levels base
{
    const int p = blockIdx.x * 256 + threadIdx.x;

    const float px = __builtin_nontemporal_load(xs + 3 * p + 0);
    const float py = __builtin_nontemporal_load(xs + 3 * p + 1);
    const float pz = __builtin_nontemporal_load(xs + 3 * p + 2);

#pragma unroll
    for (int l = 0; l < 3; ++l) {
        const uint32_t res = 16u << l;
        const float scale = (float)(res - 1u);
        const float fx = px * scale + 0.5f;
        const float fy = py * scale + 0.5f;
        const float fz = pz * scale + 0.5f;
        const float flx = floorf(fx), fly = floorf(fy), flz = floorf(fz);
        const float rx = fx - flx, ry = fy - fly, rz = fz - flz;
        const uint32_t bx = (uint32_t)flx;
        const uint32_t by = (uint32_t)fly;
        const uint32_t bz = (uint32_t)flz;

        const uint32_t* __restrict__ tl = bt + (size_t)l * kHash;

        uint32_t i0[4];
#pragma unroll
        for (int k = 0; k < 4; ++k) {
            const uint32_t oy = k & 1u, oz = (k >> 1) & 1u;
            i0[k] = bx + (by + oy) * res + (bz + oz) * res * res;
        }
        u32x2 v[4];
#pragma unroll
        for (int k = 0; k < 4; ++k)
            v[k] = *reinterpret_cast<const u32x2*>(tl + (i0[k] & ~1u));

        const bool bxodd = (bx & 1u) != 0u;   // parity(i0) == parity(bx)
        uint32_t e0[4], e1[4];
        if (bxodd) {
#pragma unroll
            for (int k = 0; k < 4; ++k) e1[k] = tl[i0[k] + 1u];
        }
#pragma unroll
        for (int k = 0; k < 4; ++k) {
            e0[k] = bxodd ? v[k].y : v[k].x;
            if (!bxodd) e1[k] = v[k].y;
        }

        const float wx0 = 1.0f - rx, wx1 = rx;
        const float wyz[4] = {(1.0f - ry) * (1.0f - rz), ry * (1.0f - rz),
                              (1.0f - ry) * rz,          ry * rz};
        float a0 = 0.0f, a1 = 0.0f;
#pragma unroll
        for (int k = 0; k < 4; ++k) {
            const float w0 = wx0 * wyz[k], w1 = wx1 * wyz[k];
            a0 = fmaf(bf_lo(e0[k]), w0, fmaf(bf_lo(e1[k]), w1, a0));
            a1 = fmaf(bf_hi(e0[k]), w0, fmaf(bf_hi(e1[k]), w1, a1));
        }

        f32x2 r; r.x = a0; r.y = a1;
        __builtin_nontemporal_store(
            r, reinterpret_cast<f32x2*>(planes + (size_t)l * kBatch * 2) + p);
    }
}

// ---- fallback (small ws): monolithic f32 kernel (R1) ----
__global__ __launch_bounds__(256) void tcnn_grid_fallback(
    const float* __restrict__ xs, const float* __restrict__ table,
    float* __restrict__ out)
{
    const int p = blockIdx.x * 256 + threadIdx.x;
    const float px = xs[3 * p + 0], py = xs[3 * p + 1], pz = xs[3 * p + 2];
    float o[16];
#pragma unroll
    for (int l = 0; l < 8; ++l) {
        const uint32_t res = 16u << l;
        const bool dense = (l < 3);
        const float scale = (float)(res - 1u);
        const float fx = px * scale + 0.5f, fy = py * scale + 0.5f,
                    fz = pz * scale + 0.5f;
        const float flx = floorf(fx), fly = floorf(fy), flz = floorf(fz);
        const float rx = fx - flx, ry = fy - fly, rz = fz - flz;
        const uint32_t bx = (uint32_t)flx, by = (uint32_t)fly,
                       bz = (uint32_t)flz;
        const float* tl = table + (size_t)l * kHash * 2u;
        float a0 = 0.0f, a1 = 0.0f;
#pragma unroll
        for (int c = 0; c < 8; ++c) {
            const uint32_t ox = c & 1u, oy = (c >> 1) & 1u, oz = (c >> 2) & 1u;
            uint32_t idx;
            if (dense)
                idx = (bx + ox) + (by + oy) * res + (bz + oz) * res * res;
            else
                idx = ((bx + ox) ^ ((by + oy) * 2654435761u) ^
                       ((bz + oz) * 805459861u)) & (kHash - 1u);
            const float2 f = *reinterpret_cast<const float2*>(tl + 2u * (size_t)idx);
            const float w = (ox ? rx : 1.0f - rx) * (oy ? ry : 1.0f - ry) *
                            (oz ? rz : 1.0f - rz);
            a0 = fmaf(f.x, w, a0);
            a1 = fmaf(f.y, w, a1);
        }
        o[2 * l] = a0; o[2 * l + 1] = a1;
    }
    float4* op = reinterpret_cast<float4*>(out + (size_t)p * 16u);
#pragma unroll
    for (int i = 0; i < 4; ++i)
        op[i] = make_float4(o[4 * i], o[4 * i + 1], o[4 * i + 2], o[4 * i + 3]);
}

extern "C" void kernel_launch(void* const* d_in, const int* in_sizes, int n_in,
                              void* d_out, int out_size, void* d_ws,
                              size_t ws_size, hipStream_t stream) {
    const float* xs    = (const float*)d_in[0];
    const float* table = (const float*)d_in[1];
    float*       out   = (float*)d_out;

    const dim3 block(256);
    const dim3 grid(kBatch / 256);

    if (ws_size < kWsNeed) {
        hipLaunchKernelGGL(tcnn_grid_fallback, grid, block, 0, stream,
                           xs, table, out);
        return;
    }

    uint32_t* bt     = (uint32_t*)d_ws;                       // 16 MB
    float*    planes = (float*)d_ws + 4u * 1024u * 1024u;     // 7 x 16 MB

    hipLaunchKernelGGL(convert_tables, dim3(kBatch / 256), block, 0, stream,
                       table, bt);
    hipLaunchKernelGGL(dense_levels_b, grid, block, 0, stream, xs, bt, planes);

    hipLaunchKernelGGL((hash_level_b<128u, false>), grid, block, 0, stream,
                       xs, bt + (size_t)3 * kHash,
                       planes + (size_t)3 * kBatch * 2, nullptr, out);
    hipLaunchKernelGGL((hash_level_b<256u, false>), grid, block, 0, stream,
                       xs, bt + (size_t)4 * kHash,
                       planes + (size_t)4 * kBatch * 2, nullptr, out);
    hipLaunchKernelGGL((hash_level_b<512u, false>), grid, block, 0, stream,
                       xs, bt + (size_t)5 * kHash,
                       planes + (size_t)5 * kBatch * 2, nullptr, out);
    hipLaunchKernelGGL((hash_level_b<1024u, false>), grid, block, 0, stream,
                       xs, bt + (size_t)6 * kHash,
                       planes + (size_t)6 * kBatch * 2, nullptr, out);
    hipLaunchKernelGGL((hash_level_b<2048u, true>), grid, block, 0, stream,
                       xs, bt + (size_t)7 * kHash,
                       nullptr, planes, out);
}

// Round 5
// 385.562 us; speedup vs baseline: 1.4101x; 1.4101x over previous
//
#include <hip/hip_runtime.h>
#include <cstdint>

// TCNN hash-grid fwd, R5:
//  - bf16-packed tables in ws (convert pre-pass, NT streams)
//  - dense levels 0-1 gathered from LDS (153 KB/block), level 2 from L2 (paired)
//  - hash levels 3-7 one kernel each (table 2 MB bf16 -> per-XCD L2 resident)
//  - direct strided f32x2 writes into out rows (L2/L3 byte-mask merge), no
//    planar ws, no interleave pass, no nontemporal on reused data.

constexpr int      kBatch  = 2097152;
constexpr uint32_t kHash   = 1u << 19;
constexpr size_t   kWsNeed = (size_t)16 * 1024 * 1024; // bf16 tables only

typedef float    f32x2 __attribute__((ext_vector_type(2)));
typedef float    f32x4 __attribute__((ext_vector_type(4)));
typedef uint32_t u32x2 __attribute__((ext_vector_type(2)));

// max reachable dense linear index: res + res^2 + res^3 (corner coord == res)
constexpr uint32_t kL0Ents = 16u + 16u * 16u + 16u * 16u * 16u + 1u;   // 4369
constexpr uint32_t kL1Ents = 32u + 32u * 32u + 32u * 32u * 32u + 1u;   // 33825

__device__ __forceinline__ uint32_t bf16rn(float f) {
    uint32_t u = __float_as_uint(f);
    return (u + 0x7FFFu + ((u >> 16) & 1u)) >> 16;
}
__device__ __forceinline__ float bf_lo(uint32_t w) {
    return __uint_as_float(w << 16);
}
__device__ __forceinline__ float bf_hi(uint32_t w) {
    return __uint_as_float(w & 0xFFFF0000u);
}

// ---- pack f32 table [8,2^19,2] -> bf16x2 words [8,2^19] ----
__global__ __launch_bounds__(256) void convert_tables(
    const float* __restrict__ table, uint32_t* __restrict__ bt)
{
    const size_t i = (size_t)blockIdx.x * 256 + threadIdx.x; // 2 entries each
    const f32x4 v = __builtin_nontemporal_load(
        reinterpret_cast<const f32x4*>(table) + i);
    u32x2 o;
    o.x = bf16rn(v.x) | (bf16rn(v.y) << 16);
    o.y = bf16rn(v.z) | (bf16rn(v.w) << 16);
    __builtin_nontemporal_store(o, reinterpret_cast<u32x2*>(bt) + i);
}

// ---- hashed level: 8 B f32x2 store into out row ----
template <uint32_t RES, int L>
__global__ __launch_bounds__(256) void hash_level_b(
    const float* __restrict__ xs,
    const uint32_t* __restrict__ tl,   // this level's bf16x2 table
    float* __restrict__ out)
{
    const int p = blockIdx.x * 256 + threadIdx.x;

    const float px = xs[3 * p + 0];
    const float py = xs[3 * p + 1];
    const float pz = xs[3 * p + 2];

    const float scale = (float)(RES - 1u);
    const float fx = px * scale + 0.5f;
    const float fy = py * scale + 0.5f;
    const float fz = pz * scale + 0.5f;
    const float flx = floorf(fx), fly = floorf(fy), flz = floorf(fz);
    const float rx = fx - flx, ry = fy - fly, rz = fz - flz;
    const uint32_t bx = (uint32_t)flx;
    const uint32_t by = (uint32_t)fly;
    const uint32_t bz = (uint32_t)flz;

    const uint32_t hy0 = by * 2654435761u, hy1 = (by + 1u) * 2654435761u;
    const uint32_t hz0 = bz * 805459861u,  hz1 = (bz + 1u) * 805459861u;
    uint32_t hyz[4] = {hy0 ^ hz0, hy1 ^ hz0, hy0 ^ hz1, hy1 ^ hz1};

    uint32_t i0[4];
#pragma unroll
    for (int k = 0; k < 4; ++k) i0[k] = (bx ^ hyz[k]) & (kHash - 1u);

    u32x2 v[4];
#pragma unroll
    for (int k = 0; k < 4; ++k)
        v[k] = *reinterpret_cast<const u32x2*>(tl + (i0[k] & ~1u));

    const bool bxodd = (bx & 1u) != 0u;
    uint32_t e0[4], e1[4];
    if (bxodd) {
#pragma unroll
        for (int k = 0; k < 4; ++k)
            e1[k] = tl[((bx + 1u) ^ hyz[k]) & (kHash - 1u)];
    }
#pragma unroll
    for (int k = 0; k < 4; ++k) {
        const bool lo = (i0[k] & 1u) != 0u;
        e0[k] = lo ? v[k].y : v[k].x;
        if (!bxodd) e1[k] = lo ? v[k].x : v[k].y;   // idx^1 partner
    }

    const float wx0 = 1.0f - rx, wx1 = rx;
    const float wyz[4] = {(1.0f - ry) * (1.0f - rz), ry * (1.0f - rz),
                          (1.0f - ry) * rz,          ry * rz};
    float a0 = 0.0f, a1 = 0.0f;
#pragma unroll
    for (int k = 0; k < 4; ++k) {
        const float w0 = wx0 * wyz[k], w1 = wx1 * wyz[k];
        a0 = fmaf(bf_lo(e0[k]), w0, fmaf(bf_lo(e1[k]), w1, a0));
        a1 = fmaf(bf_hi(e0[k]), w0, fmaf(bf_hi(e1[k]), w1, a1));
    }

    f32x2 r; r.x = a0; r.y = a1;
    reinterpret_cast<f32x2*>(out + (size_t)p * 16u)[L] = r;
}

// ---- dense levels 0-2: 0,1 from LDS; 2 from global with x-pairing ----
__global__ __launch_bounds__(1024) void dense_levels_lds(
    const float* __restrict__ xs,
    const uint32_t* __restrict__ bt,   // bf16x2 tables base
    float* __restrict__ out)
{
    __shared__ uint32_t sh[kL0Ents + kL1Ents];  // 152.8 KB

    for (uint32_t i = threadIdx.x; i < kL0Ents; i += 1024u)
        sh[i] = bt[i];
    for (uint32_t i = threadIdx.x; i < kL1Ents; i += 1024u)
        sh[kL0Ents + i] = bt[kHash + i];
    __syncthreads();

    const int p = blockIdx.x * 1024 + threadIdx.x;
    const float px = xs[3 * p + 0];
    const float py = xs[3 * p + 1];
    const float pz = xs[3 * p + 2];

    f32x2* orow = reinterpret_cast<f32x2*>(out + (size_t)p * 16u);

    // ---- levels 0,1 from LDS ----
#pragma unroll
    for (int l = 0; l < 2; ++l) {
        const uint32_t res    = (l == 0) ? 16u : 32u;
        const uint32_t shbase = (l == 0) ? 0u  : kL0Ents;
        const float scale = (float)(res - 1u);
        const float fx = px * scale + 0.5f;
        const float fy = py * scale + 0.5f;
        const float fz = pz * scale + 0.5f;
        const float flx = floorf(fx), fly = floorf(fy), flz = floorf(fz);
        const float rx = fx - flx, ry = fy - fly, rz = fz - flz;
        const uint32_t bx = (uint32_t)flx;
        const uint32_t by = (uint32_t)fly;
        const uint32_t bz = (uint32_t)flz;

        const float wx0 = 1.0f - rx, wx1 = rx;
        const float wyz[4] = {(1.0f - ry) * (1.0f - rz), ry * (1.0f - rz),
                              (1.0f - ry) * rz,          ry * rz};
        float a0 = 0.0f, a1 = 0.0f;
#pragma unroll
        for (int k = 0; k < 4; ++k) {
            const uint32_t oy = k & 1u, oz = (k >> 1) & 1u;
            const uint32_t i0 =
                bx + (by + oy) * res + (bz + oz) * res * res;
            const uint32_t eA = sh[shbase + i0];
            const uint32_t eB = sh[shbase + i0 + 1u];
            const float w0 = wx0 * wyz[k], w1 = wx1 * wyz[k];
            a0 = fmaf(bf_lo(eA), w0, fmaf(bf_lo(eB), w1, a0));
            a1 = fmaf(bf_hi(eA), w0, fmaf(bf_hi(eB), w1, a1));
        }
        f32x2 r; r.x = a0; r.y = a1;
        orow[l] = r;
    }

    // ---- level 2 (res 64) from global, x-paired ----
    {
        const uint32_t res = 64u;
        const uint32_t* __restrict__ tl = bt + (size_t)2 * kHash;
        const float scale = (float)(res - 1u);
        const float fx = px * scale + 0.5f;
        const float fy = py * scale + 0.5f;
        const float fz = pz * scale + 0.5f;
        const float flx = floorf(fx), fly = floorf(fy), flz = floorf(fz);
        const float rx = fx - flx, ry = fy - fly, rz = fz - flz;
        const uint32_t bx = (uint32_t)flx;
        const uint32_t by = (uint32_t)fly;
        const uint32_t bz = (uint32_t)flz;

        uint32_t i0[4];
#pragma unroll
        for (int k = 0; k < 4; ++k) {
            const uint32_t oy = k & 1u, oz = (k >> 1) & 1u;
            i0[k] = bx + (by + oy) * res + (bz + oz) * res * res;
        }
        u32x2 v[4];
#pragma unroll
        for (int k = 0; k < 4; ++k)
            v[k] = *reinterpret_cast<const u32x2*>(tl + (i0[k] & ~1u));

        const bool bxodd = (bx & 1u) != 0u;   // parity(i0) == parity(bx)
        uint32_t e0[4], e1[4];
        if (bxodd) {
#pragma unroll
            for (int k = 0; k < 4; ++k) e1[k] = tl[i0[k] + 1u];
        }
#pragma unroll
        for (int k = 0; k < 4; ++k) {
            e0[k] = bxodd ? v[k].y : v[k].x;
            if (!bxodd) e1[k] = v[k].y;
        }

        const float wx0 = 1.0f - rx, wx1 = rx;
        const float wyz[4] = {(1.0f - ry) * (1.0f - rz), ry * (1.0f - rz),
                              (1.0f - ry) * rz,          ry * rz};
        float a0 = 0.0f, a1 = 0.0f;
#pragma unroll
        for (int k = 0; k < 4; ++k) {
            const float w0 = wx0 * wyz[k], w1 = wx1 * wyz[k];
            a0 = fmaf(bf_lo(e0[k]), w0, fmaf(bf_lo(e1[k]), w1, a0));
            a1 = fmaf(bf_hi(e0[k]), w0, fmaf(bf_hi(e1[k]), w1, a1));
        }
        f32x2 r; r.x = a0; r.y = a1;
        orow[2] = r;
    }
}

// ---- fallback (small ws): monolithic f32 kernel (R1) ----
__global__ __launch_bounds__(256) void tcnn_grid_fallback(
    const float* __restrict__ xs, const float* __restrict__ table,
    float* __restrict__ out)
{
    const int p = blockIdx.x * 256 + threadIdx.x;
    const float px = xs[3 * p + 0], py = xs[3 * p + 1], pz = xs[3 * p + 2];
    float o[16];
#pragma unroll
    for (int l = 0; l < 8; ++l) {
        const uint32_t res = 16u << l;
        const bool dense = (l < 3);
        const float scale = (float)(res - 1u);
        const float fx = px * scale + 0.5f, fy = py * scale + 0.5f,
                    fz = pz * scale + 0.5f;
        const float flx = floorf(fx), fly = floorf(fy), flz = floorf(fz);
        const float rx = fx - flx, ry = fy - fly, rz = fz - flz;
        const uint32_t bx = (uint32_t)flx, by = (uint32_t)fly,
                       bz = (uint32_t)flz;
        const float* tl = table + (size_t)l * kHash * 2u;
        float a0 = 0.0f, a1 = 0.0f;
#pragma unroll
        for (int c = 0; c < 8; ++c) {
            const uint32_t ox = c & 1u, oy = (c >> 1) & 1u, oz = (c >> 2) & 1u;
            uint32_t idx;
            if (dense)
                idx = (bx + ox) + (by + oy) * res + (bz + oz) * res * res;
            else
                idx = ((bx + ox) ^ ((by + oy) * 2654435761u) ^
                       ((bz + oz) * 805459861u)) & (kHash - 1u);
            const float2 f = *reinterpret_cast<const float2*>(tl + 2u * (size_t)idx);
            const float w = (ox ? rx : 1.0f - rx) * (oy ? ry : 1.0f - ry) *
                            (oz ? rz : 1.0f - rz);
            a0 = fmaf(f.x, w, a0);
            a1 = fmaf(f.y, w, a1);
        }
        o[2 * l] = a0; o[2 * l + 1] = a1;
    }
    float4* op = reinterpret_cast<float4*>(out + (size_t)p * 16u);
#pragma unroll
    for (int i = 0; i < 4; ++i)
        op[i] = make_float4(o[4 * i], o[4 * i + 1], o[4 * i + 2], o[4 * i + 3]);
}

extern "C" void kernel_launch(void* const* d_in, const int* in_sizes, int n_in,
                              void* d_out, int out_size, void* d_ws,
                              size_t ws_size, hipStream_t stream) {
    const float* xs    = (const float*)d_in[0];
    const float* table = (const float*)d_in[1];
    float*       out   = (float*)d_out;

    if (ws_size < kWsNeed) {
        hipLaunchKernelGGL(tcnn_grid_fallback, dim3(kBatch / 256), dim3(256),
                           0, stream, xs, table, out);
        return;
    }

    uint32_t* bt = (uint32_t*)d_ws;   // 16 MB bf16x2 tables

    hipLaunchKernelGGL(convert_tables, dim3(kBatch / 256), dim3(256), 0,
                       stream, table, bt);

    hipLaunchKernelGGL(dense_levels_lds, dim3(kBatch / 1024), dim3(1024), 0,
                       stream, xs, bt, out);

    hipLaunchKernelGGL((hash_level_b<128u, 3>), dim3(kBatch / 256), dim3(256),
                       0, stream, xs, bt + (size_t)3 * kHash, out);
    hipLaunchKernelGGL((hash_level_b<256u, 4>), dim3(kBatch / 256), dim3(256),
                       0, stream, xs, bt + (size_t)4 * kHash, out);
    hipLaunchKernelGGL((hash_level_b<512u, 5>), dim3(kBatch / 256), dim3(256),
                       0, stream, xs, bt + (size_t)5 * kHash, out);
    hipLaunchKernelGGL((hash_level_b<1024u, 6>), dim3(kBatch / 256), dim3(256),
                       0, stream, xs, bt + (size_t)6 * kHash, out);
    hipLaunchKernelGGL((hash_level_b<2048u, 7>), dim3(kBatch / 256), dim3(256),
                       0, stream, xs, bt + (size_t)7 * kHash, out);
}

// Round 6
// 363.155 us; speedup vs baseline: 1.4971x; 1.0617x over previous
//
#include <hip/hip_runtime.h>
#include <cstdint>

// TCNN hash-grid fwd, R6:
//  - bf16-packed tables in ws (convert pre-pass)
//  - hash levels 3-7 in ONE launch (level = blockIdx>>13, ascending => one
//    2 MB table hot per XCD-L2 at a time), writing compact bf16x2 planes (ws)
//  - merge kernel: dense levels 0-1 from LDS, level 2 from L2 (x-paired),
//    5 plane reads, one full 64 B row NT write per point. No partial-line
//    output writes anywhere => no masked-line HBM write amplification.

constexpr int      kBatch  = 2097152;
constexpr uint32_t kHash   = 1u << 19;
constexpr size_t   kWsNeed = (size_t)(16 + 40) * 1024 * 1024; // tables+planes

typedef float    f32x2 __attribute__((ext_vector_type(2)));
typedef float    f32x4 __attribute__((ext_vector_type(4)));
typedef uint32_t u32x2 __attribute__((ext_vector_type(2)));

// max reachable dense linear index: res + res^2 + res^3 + 1
constexpr uint32_t kL0Ents = 16u + 16u * 16u + 16u * 16u * 16u + 1u;   // 4369
constexpr uint32_t kL1Ents = 32u + 32u * 32u + 32u * 32u * 32u + 1u;   // 33825

__device__ __forceinline__ uint32_t bf16rn(float f) {
    uint32_t u = __float_as_uint(f);
    return (u + 0x7FFFu + ((u >> 16) & 1u)) >> 16;
}
__device__ __forceinline__ float bf_lo(uint32_t w) {
    return __uint_as_float(w << 16);
}
__device__ __forceinline__ float bf_hi(uint32_t w) {
    return __uint_as_float(w & 0xFFFF0000u);
}

// ---- pack f32 table [8,2^19,2] -> bf16x2 words [8,2^19] ----
__global__ __launch_bounds__(256) void convert_tables(
    const float* __restrict__ table, uint32_t* __restrict__ bt)
{
    const size_t i = (size_t)blockIdx.x * 256 + threadIdx.x; // 2 entries each
    const f32x4 v = __builtin_nontemporal_load(
        reinterpret_cast<const f32x4*>(table) + i);
    u32x2 o;
    o.x = bf16rn(v.x) | (bf16rn(v.y) << 16);
    o.y = bf16rn(v.z) | (bf16rn(v.w) << 16);
    __builtin_nontemporal_store(o, reinterpret_cast<u32x2*>(bt) + i);
}

// ---- hash levels 3..7, single launch, bf16x2 plane output ----
__global__ __launch_bounds__(256) void hash_levels(
    const float* __restrict__ xs,
    const uint32_t* __restrict__ bt,
    uint32_t* __restrict__ planes)     // 5 x kBatch u32
{
    const uint32_t lvl = blockIdx.x >> 13;               // 0..4 -> level 3..7
    const int p = (int)(blockIdx.x & 8191u) * 256 + threadIdx.x;
    const uint32_t* __restrict__ tl = bt + (size_t)(lvl + 3u) * kHash;

    const float px = xs[3 * p + 0];
    const float py = xs[3 * p + 1];
    const float pz = xs[3 * p + 2];

    const float scale = (float)((128u << lvl) - 1u);
    const float fx = px * scale + 0.5f;
    const float fy = py * scale + 0.5f;
    const float fz = pz * scale + 0.5f;
    const float flx = floorf(fx), fly = floorf(fy), flz = floorf(fz);
    const float rx = fx - flx, ry = fy - fly, rz = fz - flz;
    const uint32_t bx = (uint32_t)flx;
    const uint32_t by = (uint32_t)fly;
    const uint32_t bz = (uint32_t)flz;

    const uint32_t hy0 = by * 2654435761u, hy1 = (by + 1u) * 2654435761u;
    const uint32_t hz0 = bz * 805459861u,  hz1 = (bz + 1u) * 805459861u;
    uint32_t hyz[4] = {hy0 ^ hz0, hy1 ^ hz0, hy0 ^ hz1, hy1 ^ hz1};

    uint32_t i0[4];
#pragma unroll
    for (int k = 0; k < 4; ++k) i0[k] = (bx ^ hyz[k]) & (kHash - 1u);

    u32x2 v[4];
#pragma unroll
    for (int k = 0; k < 4; ++k)
        v[k] = *reinterpret_cast<const u32x2*>(tl + (i0[k] & ~1u));

    const bool bxodd = (bx & 1u) != 0u;
    uint32_t e0[4], e1[4];
    if (bxodd) {
#pragma unroll
        for (int k = 0; k < 4; ++k)
            e1[k] = tl[((bx + 1u) ^ hyz[k]) & (kHash - 1u)];
    }
#pragma unroll
    for (int k = 0; k < 4; ++k) {
        const bool lo = (i0[k] & 1u) != 0u;
        e0[k] = lo ? v[k].y : v[k].x;
        if (!bxodd) e1[k] = lo ? v[k].x : v[k].y;   // idx^1 partner
    }

    const float wx0 = 1.0f - rx, wx1 = rx;
    const float wyz[4] = {(1.0f - ry) * (1.0f - rz), ry * (1.0f - rz),
                          (1.0f - ry) * rz,          ry * rz};
    float a0 = 0.0f, a1 = 0.0f;
#pragma unroll
    for (int k = 0; k < 4; ++k) {
        const float w0 = wx0 * wyz[k], w1 = wx1 * wyz[k];
        a0 = fmaf(bf_lo(e0[k]), w0, fmaf(bf_lo(e1[k]), w1, a0));
        a1 = fmaf(bf_hi(e0[k]), w0, fmaf(bf_hi(e1[k]), w1, a1));
    }

    planes[(size_t)lvl * kBatch + p] = bf16rn(a0) | (bf16rn(a1) << 16);
}

// ---- merge: dense 0-1 (LDS), 2 (global paired), + 5 planes -> full row ----
__global__ __launch_bounds__(1024) void merge_dense(
    const float* __restrict__ xs,
    const uint32_t* __restrict__ bt,
    const uint32_t* __restrict__ planes,
    float* __restrict__ out)
{
    __shared__ uint32_t sh[kL0Ents + kL1Ents];  // 152.8 KB

    for (uint32_t i = threadIdx.x; i < kL0Ents; i += 1024u)
        sh[i] = bt[i];
    for (uint32_t i = threadIdx.x; i < kL1Ents; i += 1024u)
        sh[kL0Ents + i] = bt[kHash + i];
    __syncthreads();

    const int p = blockIdx.x * 1024 + threadIdx.x;
    const float px = xs[3 * p + 0];
    const float py = xs[3 * p + 1];
    const float pz = xs[3 * p + 2];

    float row[16];

    // ---- levels 0,1 from LDS ----
#pragma unroll
    for (int l = 0; l < 2; ++l) {
        const uint32_t res    = (l == 0) ? 16u : 32u;
        const uint32_t shbase = (l == 0) ? 0u  : kL0Ents;
        const float scale = (float)(res - 1u);
        const float fx = px * scale + 0.5f;
        const float fy = py * scale + 0.5f;
        const float fz = pz * scale + 0.5f;
        const float flx = floorf(fx), fly = floorf(fy), flz = floorf(fz);
        const float rx = fx - flx, ry = fy - fly, rz = fz - flz;
        const uint32_t bx = (uint32_t)flx;
        const uint32_t by = (uint32_t)fly;
        const uint32_t bz = (uint32_t)flz;

        const float wx0 = 1.0f - rx, wx1 = rx;
        const float wyz[4] = {(1.0f - ry) * (1.0f - rz), ry * (1.0f - rz),
                              (1.0f - ry) * rz,          ry * rz};
        float a0 = 0.0f, a1 = 0.0f;
#pragma unroll
        for (int k = 0; k < 4; ++k) {
            const uint32_t oy = k & 1u, oz = (k >> 1) & 1u;
            const uint32_t i0 = bx + (by + oy) * res + (bz + oz) * res * res;
            const uint32_t eA = sh[shbase + i0];
            const uint32_t eB = sh[shbase + i0 + 1u];
            const float w0 = wx0 * wyz[k], w1 = wx1 * wyz[k];
            a0 = fmaf(bf_lo(eA), w0, fmaf(bf_lo(eB), w1, a0));
            a1 = fmaf(bf_hi(eA), w0, fmaf(bf_hi(eB), w1, a1));
        }
        row[2 * l + 0] = a0;
        row[2 * l + 1] = a1;
    }

    // ---- level 2 (res 64) from global, x-paired ----
    {
        const uint32_t res = 64u;
        const uint32_t* __restrict__ tl = bt + (size_t)2 * kHash;
        const float scale = (float)(res - 1u);
        const float fx = px * scale + 0.5f;
        const float fy = py * scale + 0.5f;
        const float fz = pz * scale + 0.5f;
        const float flx = floorf(fx), fly = floorf(fy), flz = floorf(fz);
        const float rx = fx - flx, ry = fy - fly, rz = fz - flz;
        const uint32_t bx = (uint32_t)flx;
        const uint32_t by = (uint32_t)fly;
        const uint32_t bz = (uint32_t)flz;

        uint32_t i0[4];
#pragma unroll
        for (int k = 0; k < 4; ++k) {
            const uint32_t oy = k & 1u, oz = (k >> 1) & 1u;
            i0[k] = bx + (by + oy) * res + (bz + oz) * res * res;
        }
        u32x2 v[4];
#pragma unroll
        for (int k = 0; k < 4; ++k)
            v[k] = *reinterpret_cast<const u32x2*>(tl + (i0[k] & ~1u));

        const bool bxodd = (bx & 1u) != 0u;   // parity(i0) == parity(bx)
        uint32_t e0[4], e1[4];
        if (bxodd) {
#pragma unroll
            for (int k = 0; k < 4; ++k) e1[k] = tl[i0[k] + 1u];
        }
#pragma unroll
        for (int k = 0; k < 4; ++k) {
            e0[k] = bxodd ? v[k].y : v[k].x;
            if (!bxodd) e1[k] = v[k].y;
        }

        const float wx0 = 1.0f - rx, wx1 = rx;
        const float wyz[4] = {(1.0f - ry) * (1.0f - rz), ry * (1.0f - rz),
                              (1.0f - ry) * rz,          ry * rz};
        float a0 = 0.0f, a1 = 0.0f;
#pragma unroll
        for (int k = 0; k < 4; ++k) {
            const float w0 = wx0 * wyz[k], w1 = wx1 * wyz[k];
            a0 = fmaf(bf_lo(e0[k]), w0, fmaf(bf_lo(e1[k]), w1, a0));
            a1 = fmaf(bf_hi(e0[k]), w0, fmaf(bf_hi(e1[k]), w1, a1));
        }
        row[4] = a0;
        row[5] = a1;
    }

    // ---- hash levels from planes ----
#pragma unroll
    for (int l = 0; l < 5; ++l) {
        const uint32_t w = planes[(size_t)l * kBatch + p];
        row[6 + 2 * l + 0] = bf_lo(w);
        row[6 + 2 * l + 1] = bf_hi(w);
    }

    f32x4* op = reinterpret_cast<f32x4*>(out + (size_t)p * 16u);
#pragma unroll
    for (int i = 0; i < 4; ++i) {
        f32x4 q;
        q.x = row[4 * i + 0]; q.y = row[4 * i + 1];
        q.z = row[4 * i + 2]; q.w = row[4 * i + 3];
        __builtin_nontemporal_store(q, op + i);
    }
}

// ---- fallback (small ws): monolithic f32 kernel (R1) ----
__global__ __launch_bounds__(256) void tcnn_grid_fallback(
    const float* __restrict__ xs, const float* __restrict__ table,
    float* __restrict__ out)
{
    const int p = blockIdx.x * 256 + threadIdx.x;
    const float px = xs[3 * p + 0], py = xs[3 * p + 1], pz = xs[3 * p + 2];
    float o[16];
#pragma unroll
    for (int l = 0; l < 8; ++l) {
        const uint32_t res = 16u << l;
        const bool dense = (l < 3);
        const float scale = (float)(res - 1u);
        const float fx = px * scale + 0.5f, fy = py * scale + 0.5f,
                    fz = pz * scale + 0.5f;
        const float flx = floorf(fx), fly = floorf(fy), flz = floorf(fz);
        const float rx = fx - flx, ry = fy - fly, rz = fz - flz;
        const uint32_t bx = (uint32_t)flx, by = (uint32_t)fly,
                       bz = (uint32_t)flz;
        const float* tl = table + (size_t)l * kHash * 2u;
        float a0 = 0.0f, a1 = 0.0f;
#pragma unroll
        for (int c = 0; c < 8; ++c) {
            const uint32_t ox = c & 1u, oy = (c >> 1) & 1u, oz = (c >> 2) & 1u;
            uint32_t idx;
            if (dense)
                idx = (bx + ox) + (by + oy) * res + (bz + oz) * res * res;
            else
                idx = ((bx + ox) ^ ((by + oy) * 2654435761u) ^
                       ((bz + oz) * 805459861u)) & (kHash - 1u);
            const float2 f = *reinterpret_cast<const float2*>(tl + 2u * (size_t)idx);
            const float w = (ox ? rx : 1.0f - rx) * (oy ? ry : 1.0f - ry) *
                            (oz ? rz : 1.0f - rz);
            a0 = fmaf(f.x, w, a0);
            a1 = fmaf(f.y, w, a1);
        }
        o[2 * l] = a0; o[2 * l + 1] = a1;
    }
    float4* op = reinterpret_cast<float4*>(out + (size_t)p * 16u);
#pragma unroll
    for (int i = 0; i < 4; ++i)
        op[i] = make_float4(o[4 * i], o[4 * i + 1], o[4 * i + 2], o[4 * i + 3]);
}

extern "C" void kernel_launch(void* const* d_in, const int* in_sizes, int n_in,
                              void* d_out, int out_size, void* d_ws,
                              size_t ws_size, hipStream_t stream) {
    const float* xs    = (const float*)d_in[0];
    const float* table = (const float*)d_in[1];
    float*       out   = (float*)d_out;

    if (ws_size < kWsNeed) {
        hipLaunchKernelGGL(tcnn_grid_fallback, dim3(kBatch / 256), dim3(256),
                           0, stream, xs, table, out);
        return;
    }

    uint32_t* bt     = (uint32_t*)d_ws;                 // 16 MB bf16x2 tables
    uint32_t* planes = bt + (size_t)8 * kHash;          // 5 x 8 MB bf16x2

    hipLaunchKernelGGL(convert_tables, dim3(kBatch / 256), dim3(256), 0,
                       stream, table, bt);

    hipLaunchKernelGGL(hash_levels, dim3(5 * (kBatch / 256)), dim3(256), 0,
                       stream, xs, bt, planes);

    hipLaunchKernelGGL(merge_dense, dim3(kBatch / 1024), dim3(1024), 0,
                       stream, xs, bt, planes, out);
}